// Round 2
// baseline (363.310 us; speedup 1.0000x reference)
//
#include <hip/hip_runtime.h>
#include <hip/hip_cooperative_groups.h>
#include <math.h>

namespace cg = cooperative_groups;

#define K 1024
#define SAMPLES 4096
#define S (SAMPLES - 1)

// irregular_gauss: std = exp(x<=mean ? low : high); exp(-0.5*((x-mean)/std)^2)
__device__ __forceinline__ float ig(float x, float mean, float lo, float hi) {
    float sel = (x <= mean) ? lo : hi;
    float z = (x - mean) * __expf(-sel);   // (x-mean)/exp(sel)
    return __expf(-0.5f * z * z);
}

__device__ __forceinline__ float block_reduce256(float v, float* sm) {
    #pragma unroll
    for (int o = 32; o > 0; o >>= 1) v += __shfl_down(v, o, 64);
    int lane = threadIdx.x & 63, w = threadIdx.x >> 6;
    if (lane == 0) sm[w] = v;
    __syncthreads();
    float r = 0.f;
    if (threadIdx.x == 0) r = sm[0] + sm[1] + sm[2] + sm[3];
    __syncthreads();
    return r;
}

// Single cooperative kernel: 1024 blocks x 256 threads (16 waves/CU, 4 blocks/CU
// => co-resident with VGPR<=128 via __launch_bounds__(256,4)).
// Phase 1: block k computes A[k]=sum_s smear[k,s], R[k]=S*smear[k,0];
//          blocks 0..31 zero res/env.
// Phase 2: block b computes row-b reductions (coef1[b], M[b]) AND col-b
//          reduction (colsum[b]).
// Phase 3: block b -> (sb = b&15, kc = b>>4): accumulate 16 knots of chunk kc
//          into res[s], env[s] via atomics.
// Phase 4: blocks 0..15 write out[s] = env[s]*res[s].
// No early returns: every thread reaches every grid.sync().
__global__ __launch_bounds__(256, 4) void k_fused(
    const float* __restrict__ x, const float* __restrict__ sw,
    const float* __restrict__ km, const float* __restrict__ kl, const float* __restrict__ kh,
    const float* __restrict__ em, const float* __restrict__ el, const float* __restrict__ eh,
    const float* __restrict__ pol,
    float* __restrict__ A, float* __restrict__ R,
    float* __restrict__ coef1, float* __restrict__ colsum, float* __restrict__ M,
    float* __restrict__ res, float* __restrict__ env,
    float* __restrict__ out)
{
    cg::grid_group grid = cg::this_grid();
    __shared__ float sm0[4], sm1[4];
    const int b = blockIdx.x;
    const int tid = threadIdx.x;
    const float lower = sw[0], upper = sw[1];

    // ---------------- Phase 1: smear sums + zero res/env ----------------
    {
        if (b < 32) {
            int idx = b * 256 + tid;
            if (idx < 2 * S) res[idx] = 0.f;   // res and env contiguous
        }
        const int k = b;
        float xk = x[k];
        float x_step = (upper - lower) * xk * (1.0f / SAMPLES);
        float x_low = (1.0f - lower) * xk;
        float mean = km[k], lo = kl[k], hi = kh[k];
        float sum = 0.f;
        for (int s = tid; s < S; s += 256) {
            float g = x_step * ((float)s * (1.0f / SAMPLES)) + x_low;
            sum += ig(g, mean, lo, hi);
        }
        float tot = block_reduce256(sum, sm0);
        if (tid == 0) {
            A[k] = tot;
            R[k] = (float)S * ig(x_low, mean, lo, hi);  // x_iter[0]==0
        }
    }
    grid.sync();

    // ---------------- Phase 2: entangle row + col reductions -------------
    {
        const int i = b;                 // row index == col index == b
        const float Ab = A[i];
        // row b: coef1[i] = sum_j mix_ij*cos(pol_j)*R_j ; M[i] = sum_j mix_ij
        float c = 0.f, m = 0.f;
        for (int j = tid; j < K; j += 256) {
            if (j != i) {
                float corr = Ab * A[j] * (1.0f / S);
                float mix = ig(corr, em[j], el[j], eh[j]);
                c += mix * __cosf(pol[j]) * R[j];
                m += mix;
            }
        }
        float ct = block_reduce256(c, sm0);
        float mt = block_reduce256(m, sm1);
        if (tid == 0) { coef1[i] = ct; M[i] = mt; }
        // col b: colsum[j] = sum_i R_i * mix_ij with fixed entangle params j=b
        const float meanj = em[i], loj = el[i], hij = eh[i];
        float cs = 0.f;
        for (int ii = tid; ii < K; ii += 256) {
            if (ii != i) {
                float corr = A[ii] * Ab * (1.0f / S);
                cs += R[ii] * ig(corr, meanj, loj, hij);
            }
        }
        float cst = block_reduce256(cs, sm0);
        if (tid == 0) colsum[i] = cst;
    }
    grid.sync();

    // ---------------- Phase 3: accumulate res/env ------------------------
    {
        const int sb = b & 15;           // 16 s-blocks cover S=4095
        const int kc = b >> 4;           // 64 knot chunks of 16 knots
        const int s = sb * 256 + tid;
        if (s < S) {
            float xi = (float)s * (1.0f / SAMPLES);
            float rsum = 0.f, esum = 0.f;
            const int k0 = kc * 16;
            #pragma unroll 4
            for (int k = k0; k < k0 + 16; ++k) {
                float xk = x[k];
                float x_step = (upper - lower) * xk * (1.0f / SAMPLES);
                float x_low = (1.0f - lower) * xk;
                float smear = ig(x_step * xi + x_low, km[k], kl[k], kh[k]);
                float w = coef1[k] + __sinf(pol[k]) * colsum[k] + (float)(K - 1) - M[k];
                rsum += w * smear;
                float lows = x_low;                  // (1-lower)*x
                float highs = (1.0f + upper) * xk;
                float g = (highs - lows) * xi + lows;
                esum += ig(g, xk, lows, highs);
            }
            atomicAdd(&res[s], rsum);
            atomicAdd(&env[s], esum);
        }
    }
    grid.sync();

    // ---------------- Phase 4: final multiply ----------------------------
    if (b < 16) {
        int s = b * 256 + tid;
        if (s < S) out[s] = env[s] * res[s];
    }
}

extern "C" void kernel_launch(void* const* d_in, const int* in_sizes, int n_in,
                              void* d_out, int out_size, void* d_ws, size_t ws_size,
                              hipStream_t stream)
{
    const float* x   = (const float*)d_in[0];
    const float* sw  = (const float*)d_in[1];  // smear_window [lower, upper]
    const float* km  = (const float*)d_in[2];
    const float* kl  = (const float*)d_in[3];
    const float* kh  = (const float*)d_in[4];
    const float* em  = (const float*)d_in[5];
    const float* el  = (const float*)d_in[6];
    const float* eh  = (const float*)d_in[7];
    const float* pol = (const float*)d_in[8];
    float* out = (float*)d_out;

    float* A      = (float*)d_ws;
    float* R      = A + K;
    float* coef1  = R + K;
    float* colsum = coef1 + K;
    float* M      = colsum + K;
    float* res    = M + K;        // [S]
    float* env    = res + S;      // [S] (contiguous with res; zeroed in phase 1)

    void* args[] = {
        (void*)&x, (void*)&sw, (void*)&km, (void*)&kl, (void*)&kh,
        (void*)&em, (void*)&el, (void*)&eh, (void*)&pol,
        (void*)&A, (void*)&R, (void*)&coef1, (void*)&colsum, (void*)&M,
        (void*)&res, (void*)&env, (void*)&out
    };
    hipLaunchCooperativeKernel((const void*)k_fused, dim3(K), dim3(256),
                               args, 0, stream);
}

// Round 3
// 205.763 us; speedup vs baseline: 1.7657x; 1.7657x over previous
//
#include <hip/hip_runtime.h>
#include <math.h>

#define K 1024
#define SAMPLES 4096
#define S (SAMPLES - 1)
#define NBLK 1024
#define NTHR 256

// ---- persistent device-scope sync state (NOT in d_ws => never poisoned) ----
// Monotonic counters: never reset. Each global barrier consumes NBLK tickets;
// each per-sb completion counter consumes 64 tickets per launch. Works across
// serialized launches / graph replays without reinitialization.
__device__ unsigned long long g_bar = 0ULL;
__device__ unsigned long long g_sbdone[16] = {};

// irregular_gauss: std = exp(x<=mean ? low : high); exp(-0.5*((x-mean)/std)^2)
__device__ __forceinline__ float ig(float x, float mean, float lo, float hi) {
    float sel = (x <= mean) ? lo : hi;
    float z = (x - mean) * __expf(-sel);   // (x-mean)/exp(sel)
    return __expf(-0.5f * z * z);
}

// agent-scope atomic access: bypasses the non-coherent per-XCD L2s, lands at
// the coherent point. All cross-phase data goes through these.
__device__ __forceinline__ void ast(float* p, float v) {
    __hip_atomic_store(p, v, __ATOMIC_RELAXED, __HIP_MEMORY_SCOPE_AGENT);
}
__device__ __forceinline__ float ald(const float* p) {
    return __hip_atomic_load(p, __ATOMIC_RELAXED, __HIP_MEMORY_SCOPE_AGENT);
}

__device__ __forceinline__ float block_reduce256(float v, float* sm) {
    #pragma unroll
    for (int o = 32; o > 0; o >>= 1) v += __shfl_down(v, o, 64);
    int lane = threadIdx.x & 63, w = threadIdx.x >> 6;
    if (lane == 0) sm[w] = v;
    __syncthreads();
    float r = 0.f;
    if (threadIdx.x == 0) r = sm[0] + sm[1] + sm[2] + sm[3];
    __syncthreads();
    return r;
}

// Hand-rolled grid barrier: agent-scope atomics only (no L2 flush stampede,
// unlike cg::grid.sync which cost ~90us/sync here). tid0 of each block takes a
// monotonic ticket; barrier g globally spans tickets [g*NBLK,(g+1)*NBLK).
// ACQ_REL on the fetch_add + ACQUIRE on the spin load gives the release/
// acquire chain that makes pre-barrier agent-scope atomic stores visible to
// post-barrier agent-scope atomic loads.
__device__ __forceinline__ void gridbar() {
    __syncthreads();
    if (threadIdx.x == 0) {
        unsigned long long t = __hip_atomic_fetch_add(
            &g_bar, 1ULL, __ATOMIC_ACQ_REL, __HIP_MEMORY_SCOPE_AGENT);
        unsigned long long target = (t / NBLK + 1ULL) * NBLK;
        while (__hip_atomic_load(&g_bar, __ATOMIC_ACQUIRE,
                                 __HIP_MEMORY_SCOPE_AGENT) < target)
            __builtin_amdgcn_s_sleep(2);
    }
    __syncthreads();
}

// Single dispatch, 1024 blocks x 256 threads. Cooperative launch is used ONLY
// for the co-residency guarantee; sync is our own.
// Phase 0: block b: A[b]=sum_s smear[b,s], R[b]=S*smear[b,0]; blocks 0..31
//          zero res/env (atomic stores; the workspace is poisoned each iter).
// Phase 1: block b: row-b reductions (coef1[b], M[b]) and col-b (colsum[b]).
// Phase 2: block b -> (sb=b&15, kc=b>>4): accumulate 16 knots into res/env;
//          64th finisher per sb writes out[s]=env*res for its s-range.
__global__ __launch_bounds__(NTHR) void k_fused(
    const float* __restrict__ x, const float* __restrict__ sw,
    const float* __restrict__ km, const float* __restrict__ kl, const float* __restrict__ kh,
    const float* __restrict__ em, const float* __restrict__ el, const float* __restrict__ eh,
    const float* __restrict__ pol,
    float* __restrict__ A, float* __restrict__ R,
    float* __restrict__ coef1, float* __restrict__ colsum, float* __restrict__ M,
    float* __restrict__ res, float* __restrict__ env,
    float* __restrict__ out)
{
    __shared__ float sm0[4], sm1[4];
    __shared__ unsigned long long tk_sh;
    const int b = blockIdx.x;
    const int tid = threadIdx.x;
    const float lower = sw[0], upper = sw[1];
    const float inv_s = 1.0f / (float)S;

    // ---------------- Phase 0 ----------------
    {
        if (b < 32) {                       // zero res+env (contiguous 2*S)
            int idx = b * 256 + tid;
            if (idx < 2 * S) ast(&res[idx], 0.f);
        }
        float xk = x[b];
        float x_step = (upper - lower) * xk * (1.0f / SAMPLES);
        float x_low = (1.0f - lower) * xk;
        float mean = km[b], lo = kl[b], hi = kh[b];
        float sum = 0.f;
        for (int s = tid; s < S; s += 256) {
            float g = x_step * ((float)s * (1.0f / SAMPLES)) + x_low;
            sum += ig(g, mean, lo, hi);
        }
        float tot = block_reduce256(sum, sm0);
        if (tid == 0) {
            ast(&A[b], tot);
            ast(&R[b], (float)S * ig(x_low, mean, lo, hi));  // x_iter[0]==0
        }
    }
    gridbar();

    // ---------------- Phase 1: entangle row + col ----------------
    {
        const float Ab = ald(&A[b]);
        // row b: coef1[b] = sum_j mix_bj*cos(pol_j)*R_j ; M[b] = sum_j mix_bj
        float c = 0.f, m = 0.f;
        #pragma unroll
        for (int t = 0; t < 4; ++t) {
            int j = tid + t * 256;
            float Aj = ald(&A[j]);
            float Rj = ald(&R[j]);
            if (j != b) {
                float corr = Ab * Aj * inv_s;
                float mix = ig(corr, em[j], el[j], eh[j]);
                c += mix * __cosf(pol[j]) * Rj;
                m += mix;
            }
        }
        float ct = block_reduce256(c, sm0);
        float mt = block_reduce256(m, sm1);
        if (tid == 0) { ast(&coef1[b], ct); ast(&M[b], mt); }
        // col b: colsum[b] = sum_i R_i * mix_ib (entangle params fixed at b)
        const float meanb = em[b], lob = el[b], hib = eh[b];
        float cs = 0.f;
        #pragma unroll
        for (int t = 0; t < 4; ++t) {
            int i = tid + t * 256;
            float Ai = ald(&A[i]);
            float Ri = ald(&R[i]);
            if (i != b) cs += Ri * ig(Ai * Ab * inv_s, meanb, lob, hib);
        }
        float cst = block_reduce256(cs, sm0);
        if (tid == 0) ast(&colsum[b], cst);
    }
    gridbar();

    // ---------------- Phase 2: accumulate + fused final ----------------
    {
        const int sb = b & 15;            // 16 s-blocks cover S=4095
        const int kc = b >> 4;            // 64 knot chunks of 16 knots
        const int s = sb * 256 + tid;
        float xi = (float)s * (1.0f / SAMPLES);
        float rsum = 0.f, esum = 0.f;
        const int k0 = kc * 16;
        #pragma unroll 4
        for (int k = k0; k < k0 + 16; ++k) {
            float xk = x[k];
            float x_step = (upper - lower) * xk * (1.0f / SAMPLES);
            float x_low = (1.0f - lower) * xk;
            float smear = ig(x_step * xi + x_low, km[k], kl[k], kh[k]);
            float w = ald(&coef1[k]) + __sinf(pol[k]) * ald(&colsum[k])
                    + (float)(K - 1) - ald(&M[k]);
            rsum += w * smear;
            float lows = x_low;                  // (1-lower)*x
            float highs = (1.0f + upper) * xk;
            float g = (highs - lows) * xi + lows;
            esum += ig(g, xk, lows, highs);
        }
        if (s < S) {
            atomicAdd(&res[s], rsum);            // device-scope by default
            atomicAdd(&env[s], esum);
        }
        // completion counter per sb: 64th finisher multiplies this s-range.
        __syncthreads();
        if (tid == 0)
            tk_sh = __hip_atomic_fetch_add(&g_sbdone[sb], 1ULL,
                                           __ATOMIC_ACQ_REL, __HIP_MEMORY_SCOPE_AGENT);
        __syncthreads();
        if ((tk_sh & 63ULL) == 63ULL) {
            if (s < S) out[s] = ald(&env[s]) * ald(&res[s]);
        }
    }
}

extern "C" void kernel_launch(void* const* d_in, const int* in_sizes, int n_in,
                              void* d_out, int out_size, void* d_ws, size_t ws_size,
                              hipStream_t stream)
{
    const float* x   = (const float*)d_in[0];
    const float* sw  = (const float*)d_in[1];  // smear_window [lower, upper]
    const float* km  = (const float*)d_in[2];
    const float* kl  = (const float*)d_in[3];
    const float* kh  = (const float*)d_in[4];
    const float* em  = (const float*)d_in[5];
    const float* el  = (const float*)d_in[6];
    const float* eh  = (const float*)d_in[7];
    const float* pol = (const float*)d_in[8];
    float* out = (float*)d_out;

    float* A      = (float*)d_ws;
    float* R      = A + K;
    float* coef1  = R + K;
    float* colsum = coef1 + K;
    float* M      = colsum + K;
    float* res    = M + K;        // [S]
    float* env    = res + S;      // [S] (contiguous with res)

    void* args[] = {
        (void*)&x, (void*)&sw, (void*)&km, (void*)&kl, (void*)&kh,
        (void*)&em, (void*)&el, (void*)&eh, (void*)&pol,
        (void*)&A, (void*)&R, (void*)&coef1, (void*)&colsum, (void*)&M,
        (void*)&res, (void*)&env, (void*)&out
    };
    hipLaunchCooperativeKernel((const void*)k_fused, dim3(NBLK), dim3(NTHR),
                               args, 0, stream);
}

// Round 4
// 128.663 us; speedup vs baseline: 2.8237x; 1.5992x over previous
//
#include <hip/hip_runtime.h>
#include <math.h>

#define K 1024
#define SAMPLES 4096
#define S (SAMPLES - 1)
#define NBLK 256
#define NTHR 256
#define NCTR 8
#define PER_CTR (NBLK / NCTR)   // 32 arrivals per counter per barrier

// ---- persistent sync state (device globals: NOT in d_ws => never poisoned) --
// Monotonic split arrival counters, padded to separate cache lines. Each
// barrier consumes PER_CTR tickets per counter; generation is derived from a
// block's own ticket (t / PER_CTR), so no reset is needed across launches,
// graph replays, or rocprof passes.
struct __align__(256) Ctr { unsigned long long v; unsigned long long pad[31]; };
__device__ Ctr g_arr[NCTR] = {};

// irregular_gauss: std = exp(x<=mean ? low : high); exp(-0.5*((x-mean)/std)^2)
__device__ __forceinline__ float ig(float x, float mean, float lo, float hi) {
    float sel = (x <= mean) ? lo : hi;
    float z = (x - mean) * __expf(-sel);   // (x-mean)/exp(sel)
    return __expf(-0.5f * z * z);
}

// agent-scope relaxed atomics: cache-bypassing, land at the coherent point.
// All cross-phase data moves through these (so barrier needs no L2 flushes).
__device__ __forceinline__ void ast(float* p, float v) {
    __hip_atomic_store(p, v, __ATOMIC_RELAXED, __HIP_MEMORY_SCOPE_AGENT);
}
__device__ __forceinline__ float ald(const float* p) {
    return __hip_atomic_load(p, __ATOMIC_RELAXED, __HIP_MEMORY_SCOPE_AGENT);
}

__device__ __forceinline__ float wave_reduce(float v) {
    #pragma unroll
    for (int o = 32; o > 0; o >>= 1) v += __shfl_down(v, o, 64);
    return v;   // total in lane 0
}

// Grid barrier v2: RELEASE arrival on one of 8 padded counters (32 serialized
// RMWs/line, not 1024 on one line); RELAXED spin (no per-poll cache
// invalidates -- the round-3 killer); ONE agent acquire-fence per block on
// exit. Lanes 0..7 of wave 0 each watch one counter; ballot until all done.
__device__ __forceinline__ void gridbar() {
    __syncthreads();
    if (threadIdx.x < 64) {
        const int lane = threadIdx.x;
        unsigned long long target = 0ULL;
        if (lane == 0) {
            unsigned long long t = __hip_atomic_fetch_add(
                &g_arr[blockIdx.x & (NCTR - 1)].v, 1ULL,
                __ATOMIC_RELEASE, __HIP_MEMORY_SCOPE_AGENT);
            target = (t / PER_CTR + 1ULL) * PER_CTR;
        }
        target = __shfl(target, 0, 64);
        for (;;) {
            bool pending = false;
            if (lane < NCTR)
                pending = __hip_atomic_load(&g_arr[lane].v, __ATOMIC_RELAXED,
                                            __HIP_MEMORY_SCOPE_AGENT) < target;
            if (__ballot(pending) == 0ULL) break;
            __builtin_amdgcn_s_sleep(1);
        }
        __builtin_amdgcn_fence(__ATOMIC_ACQUIRE, "agent");
    }
    __syncthreads();
}

// Single dispatch, 256 blocks x 256 threads (1 block/CU).
// Phase 0: wave w of block b -> knot k=4b+w: A[k]=sum_s smear, R[k]=S*smear[k,0].
// Phase 1: stage A,R,cos(pol)*R to LDS; wave w -> row/col k=4b+w:
//          coef1[k], M[k], colsum[k].
// Phase 2: stage w[k]=coef1+sin*colsum+(K-1)-M to LDS; block b owns s in
//          [16b,16b+16): 16 s-lanes x 16 k-partials, shuffle+LDS reduce,
//          write out[s]=env*res directly. No atomics, no res/env arrays,
//          no third barrier.
__global__ __launch_bounds__(NTHR) void k_fused(
    const float* __restrict__ x, const float* __restrict__ sw,
    const float* __restrict__ km, const float* __restrict__ kl, const float* __restrict__ kh,
    const float* __restrict__ em, const float* __restrict__ el, const float* __restrict__ eh,
    const float* __restrict__ pol,
    float* __restrict__ A, float* __restrict__ R,
    float* __restrict__ coef1, float* __restrict__ colsum, float* __restrict__ M,
    float* __restrict__ out)
{
    __shared__ float lsA[K];   // phase1: A      ; phase2: w
    __shared__ float lsR[K];   // phase1: R
    __shared__ float lsC[K];   // phase1: cos(pol)*R
    __shared__ float red[2][4][16];
    const int b = blockIdx.x, tid = threadIdx.x;
    const int lane = tid & 63, wv = tid >> 6;
    const float lower = sw[0], upper = sw[1];
    const float inv_s = 1.0f / (float)S;

    // ---------------- Phase 0: per-knot smear sums ----------------
    {
        const int k = 4 * b + wv;
        float xk = x[k];
        float x_step = (upper - lower) * xk * (1.0f / SAMPLES);
        float x_low = (1.0f - lower) * xk;
        float mean = km[k], lo = kl[k], hi = kh[k];
        float sum = 0.f;
        #pragma unroll 4
        for (int s = lane; s < S; s += 64) {
            float g = x_step * ((float)s * (1.0f / SAMPLES)) + x_low;
            sum += ig(g, mean, lo, hi);
        }
        float tot = wave_reduce(sum);
        if (lane == 0) {
            ast(&A[k], tot);
            ast(&R[k], (float)S * ig(x_low, mean, lo, hi));  // x_iter[0]==0
        }
    }
    gridbar();

    // ---------------- Phase 1: entangle row+col reductions ----------------
    {
        #pragma unroll
        for (int q = 0; q < 4; ++q) {     // stage A,R,cos(pol)*R once per block
            int k = tid + q * 256;
            float a = ald(&A[k]);
            float r = ald(&R[k]);
            lsA[k] = a;
            lsR[k] = r;
            lsC[k] = __cosf(pol[k]) * r;
        }
        __syncthreads();
        const int k = 4 * b + wv;
        const float Ak = lsA[k];
        const float meank = em[k], lok = el[k], hik = eh[k];
        float c = 0.f, m = 0.f, cs = 0.f;
        #pragma unroll 4
        for (int j = lane; j < K; j += 64) {
            float corr = Ak * lsA[j] * inv_s;
            if (j != k) {
                float mix = ig(corr, em[j], el[j], eh[j]);   // row: params of j
                c += mix * lsC[j];
                m += mix;
                cs += lsR[j] * ig(corr, meank, lok, hik);    // col: params of k
            }
        }
        c = wave_reduce(c); m = wave_reduce(m); cs = wave_reduce(cs);
        if (lane == 0) { ast(&coef1[k], c); ast(&M[k], m); ast(&colsum[k], cs); }
    }
    gridbar();

    // ---------------- Phase 2: accumulate + final multiply ----------------
    {
        #pragma unroll
        for (int q = 0; q < 4; ++q) {     // stage w[k] once per block
            int k = tid + q * 256;
            lsA[k] = ald(&coef1[k]) + __sinf(pol[k]) * ald(&colsum[k])
                   + (float)(K - 1) - ald(&M[k]);
        }
        __syncthreads();
        const int sl = tid & 15;          // s-lane within block
        const int kp = tid >> 4;          // 16 k-partials of 64 knots each
        const int s = b * 16 + sl;
        const float xi = (float)s * (1.0f / SAMPLES);
        float rsum = 0.f, esum = 0.f;
        const int k0 = kp * 64;
        #pragma unroll 4
        for (int i = 0; i < 64; ++i) {
            int k = k0 + ((i + kp) & 63);    // stagger: avoids 4-way LDS bank conflict
            float xk = x[k];
            float x_step = (upper - lower) * xk * (1.0f / SAMPLES);
            float x_low = (1.0f - lower) * xk;
            float smear = ig(x_step * xi + x_low, km[k], kl[k], kh[k]);
            rsum += lsA[k] * smear;
            float highs = (1.0f + upper) * xk;
            float g = (highs - x_low) * xi + x_low;
            esum += ig(g, xk, x_low, highs);
        }
        // reduce 16 partials per s: in-wave (kp pairs 2 apart then 1 apart)...
        rsum += __shfl_down(rsum, 32, 64); rsum += __shfl_down(rsum, 16, 64);
        esum += __shfl_down(esum, 32, 64); esum += __shfl_down(esum, 16, 64);
        if (lane < 16) { red[0][wv][lane] = rsum; red[1][wv][lane] = esum; }
        __syncthreads();
        // ...then across the 4 waves
        if (tid < 16) {
            float r = red[0][0][tid] + red[0][1][tid] + red[0][2][tid] + red[0][3][tid];
            float e = red[1][0][tid] + red[1][1][tid] + red[1][2][tid] + red[1][3][tid];
            int s2 = b * 16 + tid;
            if (s2 < S) out[s2] = e * r;
        }
    }
}

extern "C" void kernel_launch(void* const* d_in, const int* in_sizes, int n_in,
                              void* d_out, int out_size, void* d_ws, size_t ws_size,
                              hipStream_t stream)
{
    const float* x   = (const float*)d_in[0];
    const float* sw  = (const float*)d_in[1];  // smear_window [lower, upper]
    const float* km  = (const float*)d_in[2];
    const float* kl  = (const float*)d_in[3];
    const float* kh  = (const float*)d_in[4];
    const float* em  = (const float*)d_in[5];
    const float* el  = (const float*)d_in[6];
    const float* eh  = (const float*)d_in[7];
    const float* pol = (const float*)d_in[8];
    float* out = (float*)d_out;

    float* A      = (float*)d_ws;
    float* R      = A + K;
    float* coef1  = R + K;
    float* colsum = coef1 + K;
    float* M      = colsum + K;

    void* args[] = {
        (void*)&x, (void*)&sw, (void*)&km, (void*)&kl, (void*)&kh,
        (void*)&em, (void*)&el, (void*)&eh, (void*)&pol,
        (void*)&A, (void*)&R, (void*)&coef1, (void*)&colsum, (void*)&M,
        (void*)&out
    };
    hipLaunchCooperativeKernel((const void*)k_fused, dim3(NBLK), dim3(NTHR),
                               args, 0, stream);
}

// Round 5
// 86.527 us; speedup vs baseline: 4.1988x; 1.4870x over previous
//
#include <hip/hip_runtime.h>
#include <math.h>

#define K 1024
#define SAMPLES 4096
#define S (SAMPLES - 1)

// irregular_gauss: std = exp(x<=mean ? low : high); exp(-0.5*((x-mean)/std)^2)
__device__ __forceinline__ float ig(float x, float mean, float lo, float hi) {
    float sel = (x <= mean) ? lo : hi;
    float z = (x - mean) * __expf(-sel);   // (x-mean)/exp(sel)
    return __expf(-0.5f * z * z);
}

__device__ __forceinline__ float wave_reduce(float v) {
    #pragma unroll
    for (int o = 32; o > 0; o >>= 1) v += __shfl_down(v, o, 64);
    return v;   // total in lane 0
}

// ---------------- Kernel 1: per-knot smear sums ----------------
// Block k: A[k] = sum_s smear[k,s]; R[k] = S*smear[k,0]  (= sum_sig.real)
__global__ __launch_bounds__(256) void k_smear(
    const float* __restrict__ x, const float* __restrict__ sw,
    const float* __restrict__ km, const float* __restrict__ kl, const float* __restrict__ kh,
    float* __restrict__ A, float* __restrict__ R)
{
    __shared__ float sm[4];
    const int k = blockIdx.x, tid = threadIdx.x;
    const float lower = sw[0], upper = sw[1];
    float xk = x[k];
    float x_step = (upper - lower) * xk * (1.0f / SAMPLES);
    float x_low = (1.0f - lower) * xk;
    float mean = km[k], lo = kl[k], hi = kh[k];
    float sum = 0.f;
    #pragma unroll 4
    for (int s = tid; s < S; s += 256) {
        float g = x_step * ((float)s * (1.0f / SAMPLES)) + x_low;
        sum += ig(g, mean, lo, hi);
    }
    sum = wave_reduce(sum);
    int lane = tid & 63, wv = tid >> 6;
    if (lane == 0) sm[wv] = sum;
    __syncthreads();
    if (tid == 0) {
        A[k] = sm[0] + sm[1] + sm[2] + sm[3];
        R[k] = (float)S * ig(x_low, mean, lo, hi);   // x_iter[0]==0
    }
}

// ---------------- Kernel 2: entangle row+col -> single weight w[b] ---------
// Block b: coef1 = sum_j mix_bj cos(pol_j) R_j ; M = sum_j mix_bj ;
//          colsum = sum_i R_i mix_ib ;
//          w[b] = coef1 + sin(pol_b)*colsum + (K-1) - M.
__global__ __launch_bounds__(256) void k_entangle(
    const float* __restrict__ A, const float* __restrict__ R,
    const float* __restrict__ em, const float* __restrict__ el, const float* __restrict__ eh,
    const float* __restrict__ pol,
    float* __restrict__ w)
{
    __shared__ float lsA[K], lsR[K], lsC[K];
    __shared__ float sm0[4], sm1[4], sm2[4];
    const int b = blockIdx.x, tid = threadIdx.x;
    const float inv_s = 1.0f / (float)S;
    #pragma unroll
    for (int q = 0; q < 4; ++q) {            // stage A, R, cos(pol)*R
        int j = tid + q * 256;
        float a = A[j], r = R[j];
        lsA[j] = a; lsR[j] = r; lsC[j] = __cosf(pol[j]) * r;
    }
    __syncthreads();
    const float Ab = lsA[b];
    const float meanb = em[b], lob = el[b], hib = eh[b];
    float c = 0.f, m = 0.f, cs = 0.f;
    #pragma unroll
    for (int q = 0; q < 4; ++q) {
        int j = tid + q * 256;
        if (j != b) {
            float corr = Ab * lsA[j] * inv_s;
            float mix = ig(corr, em[j], el[j], eh[j]);   // row: params of j
            c += mix * lsC[j];
            m += mix;
            cs += lsR[j] * ig(corr, meanb, lob, hib);    // col: params of b
        }
    }
    c = wave_reduce(c); m = wave_reduce(m); cs = wave_reduce(cs);
    int lane = tid & 63, wv = tid >> 6;
    if (lane == 0) { sm0[wv] = c; sm1[wv] = m; sm2[wv] = cs; }
    __syncthreads();
    if (tid == 0) {
        float ct = sm0[0] + sm0[1] + sm0[2] + sm0[3];
        float mt = sm1[0] + sm1[1] + sm1[2] + sm1[3];
        float cst = sm2[0] + sm2[1] + sm2[2] + sm2[3];
        w[b] = ct + __sinf(pol[b]) * cst + (float)(K - 1) - mt;
    }
}

// ---------------- Kernel 3: accumulate + final multiply ----------------
// Block b exclusively owns s in [16b, 16b+16): 16 s-lanes x 16 k-partials
// (64 knots each), shuffle+LDS reduce, out[s] = env*res. No atomics.
__global__ __launch_bounds__(256) void k_accum(
    const float* __restrict__ x, const float* __restrict__ sw,
    const float* __restrict__ km, const float* __restrict__ kl, const float* __restrict__ kh,
    const float* __restrict__ w,
    float* __restrict__ out)
{
    __shared__ float lsW[K];
    __shared__ float red[2][4][16];
    const int b = blockIdx.x, tid = threadIdx.x;
    const int lane = tid & 63, wv = tid >> 6;
    const float lower = sw[0], upper = sw[1];
    #pragma unroll
    for (int q = 0; q < 4; ++q) { int k = tid + q * 256; lsW[k] = w[k]; }
    __syncthreads();
    const int sl = tid & 15;          // s-lane within block
    const int kp = tid >> 4;          // 16 k-partials of 64 knots each
    const int s = b * 16 + sl;
    const float xi = (float)s * (1.0f / SAMPLES);
    float rsum = 0.f, esum = 0.f;
    const int k0 = kp * 64;
    #pragma unroll 4
    for (int i = 0; i < 64; ++i) {
        int k = k0 + ((i + kp) & 63);    // stagger: LDS conflict-free across kp
        float xk = x[k];
        float x_step = (upper - lower) * xk * (1.0f / SAMPLES);
        float x_low = (1.0f - lower) * xk;
        float smear = ig(x_step * xi + x_low, km[k], kl[k], kh[k]);
        rsum += lsW[k] * smear;
        float highs = (1.0f + upper) * xk;
        float g = (highs - x_low) * xi + x_low;
        esum += ig(g, xk, x_low, highs);
    }
    // lanes: lane = kp_low*16 + sl ; fold kp_low 0..3 into lanes 0..15
    rsum += __shfl_down(rsum, 32, 64); rsum += __shfl_down(rsum, 16, 64);
    esum += __shfl_down(esum, 32, 64); esum += __shfl_down(esum, 16, 64);
    if (lane < 16) { red[0][wv][lane] = rsum; red[1][wv][lane] = esum; }
    __syncthreads();
    if (tid < 16) {
        float r = red[0][0][tid] + red[0][1][tid] + red[0][2][tid] + red[0][3][tid];
        float e = red[1][0][tid] + red[1][1][tid] + red[1][2][tid] + red[1][3][tid];
        int s2 = b * 16 + tid;
        if (s2 < S) out[s2] = e * r;
    }
}

extern "C" void kernel_launch(void* const* d_in, const int* in_sizes, int n_in,
                              void* d_out, int out_size, void* d_ws, size_t ws_size,
                              hipStream_t stream)
{
    const float* x   = (const float*)d_in[0];
    const float* sw  = (const float*)d_in[1];  // smear_window [lower, upper]
    const float* km  = (const float*)d_in[2];
    const float* kl  = (const float*)d_in[3];
    const float* kh  = (const float*)d_in[4];
    const float* em  = (const float*)d_in[5];
    const float* el  = (const float*)d_in[6];
    const float* eh  = (const float*)d_in[7];
    const float* pol = (const float*)d_in[8];
    float* out = (float*)d_out;

    float* A = (float*)d_ws;
    float* R = A + K;
    float* w = R + K;

    k_smear<<<K, 256, 0, stream>>>(x, sw, km, kl, kh, A, R);
    k_entangle<<<K, 256, 0, stream>>>(A, R, em, el, eh, pol, w);
    k_accum<<<256, 256, 0, stream>>>(x, sw, km, kl, kh, w, out);
}

// Round 6
// 84.182 us; speedup vs baseline: 4.3158x; 1.0279x over previous
//
#include <hip/hip_runtime.h>
#include <math.h>

#define K 1024
#define SAMPLES 4096
#define S (SAMPLES - 1)

__device__ __forceinline__ float wave_reduce(float v) {
    #pragma unroll
    for (int o = 32; o > 0; o >>= 1) v += __shfl_down(v, o, 64);
    return v;   // total in lane 0
}

// gaussian with PRE-INVERTED sigma: exp(-0.5*((x-mean)*is)^2), is = exp(-sel)
__device__ __forceinline__ float gph(float x, float mean, float islo, float ishi) {
    float z = (x - mean) * ((x <= mean) ? islo : ishi);
    return __expf(-0.5f * z * z);
}

// ---------------- Kernel 1: per-knot smear sums + per-knot exp table --------
// Block k: A[k] = sum_s smear[k,s]; R[k] = S*smear[k,0].
// Also precomputes the 6 per-knot inverse sigmas so downstream kernels pay
// ONE exp per gaussian instead of two:
//   elo/ehi   = exp(-kl), exp(-kh)               (smear)
//   eel/eeh   = exp(-el), exp(-eh)               (entangle mix)
//   eglo/eghi = exp(-(1-lower)x), exp(-(1+upper)x) (envelope)
__global__ __launch_bounds__(256) void k_smear(
    const float* __restrict__ x, const float* __restrict__ sw,
    const float* __restrict__ km, const float* __restrict__ kl, const float* __restrict__ kh,
    const float* __restrict__ el, const float* __restrict__ eh,
    float* __restrict__ A, float* __restrict__ R,
    float* __restrict__ elo, float* __restrict__ ehi,
    float* __restrict__ eel, float* __restrict__ eeh,
    float* __restrict__ eglo, float* __restrict__ eghi)
{
    __shared__ float sm[4];
    const int k = blockIdx.x, tid = threadIdx.x;
    const float lower = sw[0], upper = sw[1];
    const float xk = x[k];
    const float x_step = (upper - lower) * xk * (1.0f / SAMPLES);
    const float x_low = (1.0f - lower) * xk;
    const float mean = km[k];
    const float islo = __expf(-kl[k]), ishi = __expf(-kh[k]);  // hoisted!
    float sum = 0.f;
    #pragma unroll 4
    for (int s = tid; s < S; s += 256) {
        float g = x_step * ((float)s * (1.0f / SAMPLES)) + x_low;
        sum += gph(g, mean, islo, ishi);
    }
    sum = wave_reduce(sum);
    int lane = tid & 63, wv = tid >> 6;
    if (lane == 0) sm[wv] = sum;
    __syncthreads();
    if (tid == 0) {
        A[k] = sm[0] + sm[1] + sm[2] + sm[3];
        R[k] = (float)S * gph(x_low, mean, islo, ishi);   // x_iter[0]==0
        elo[k] = islo; ehi[k] = ishi;
        eel[k] = __expf(-el[k]); eeh[k] = __expf(-eh[k]);
        eglo[k] = __expf(-x_low); eghi[k] = __expf(-(1.0f + upper) * xk);
    }
}

// ---------------- Kernel 2: entangle row+col -> single weight w[b] ---------
// Block b: coef1 = sum_j mix_bj cos(pol_j) R_j ; M = sum_j mix_bj ;
//          colsum = sum_i R_i mix_ib ;
//          w[b] = coef1 + sin(pol_b)*colsum + (K-1) - M.
// Inverse sigmas come precomputed from k_smear: 2 exps per j, not 4.
__global__ __launch_bounds__(256) void k_entangle(
    const float* __restrict__ A, const float* __restrict__ R,
    const float* __restrict__ em, const float* __restrict__ eel, const float* __restrict__ eeh,
    const float* __restrict__ pol,
    float* __restrict__ w)
{
    __shared__ float lsA[K], lsC[K], lsR[K], lsEm[K], lsEl[K], lsEh[K];
    __shared__ float sm0[4], sm1[4], sm2[4];
    const int b = blockIdx.x, tid = threadIdx.x;
    const float inv_s = 1.0f / (float)S;
    #pragma unroll
    for (int q = 0; q < 4; ++q) {            // stage once per block
        int j = tid + q * 256;
        float r = R[j];
        lsA[j] = A[j]; lsR[j] = r; lsC[j] = __cosf(pol[j]) * r;
        lsEm[j] = em[j]; lsEl[j] = eel[j]; lsEh[j] = eeh[j];
    }
    __syncthreads();
    const float Ab = lsA[b];
    const float meanb = lsEm[b], isblo = lsEl[b], isbhi = lsEh[b];
    float c = 0.f, m = 0.f, cs = 0.f;
    #pragma unroll
    for (int q = 0; q < 4; ++q) {
        int j = tid + q * 256;
        if (j != b) {
            float corr = Ab * lsA[j] * inv_s;
            float mix = gph(corr, lsEm[j], lsEl[j], lsEh[j]);   // row: params of j
            c += mix * lsC[j];
            m += mix;
            cs += lsR[j] * gph(corr, meanb, isblo, isbhi);      // col: params of b
        }
    }
    c = wave_reduce(c); m = wave_reduce(m); cs = wave_reduce(cs);
    int lane = tid & 63, wv = tid >> 6;
    if (lane == 0) { sm0[wv] = c; sm1[wv] = m; sm2[wv] = cs; }
    __syncthreads();
    if (tid == 0) {
        float ct = sm0[0] + sm0[1] + sm0[2] + sm0[3];
        float mt = sm1[0] + sm1[1] + sm1[2] + sm1[3];
        float cst = sm2[0] + sm2[1] + sm2[2] + sm2[3];
        w[b] = ct + __sinf(pol[b]) * cst + (float)(K - 1) - mt;
    }
}

// ---------------- Kernel 3: accumulate + final multiply ----------------
// Block b exclusively owns s in [16b, 16b+16): 16 s-lanes x 16 k-partials
// (64 knots each), shuffle+LDS reduce, out[s] = env*res. No atomics.
// All per-knot quantities staged in LDS with precomputed inverse sigmas:
// inner loop is 2 exps per (s,k), not 4.
__global__ __launch_bounds__(256) void k_accum(
    const float* __restrict__ x, const float* __restrict__ sw,
    const float* __restrict__ km,
    const float* __restrict__ elo, const float* __restrict__ ehi,
    const float* __restrict__ eglo, const float* __restrict__ eghi,
    const float* __restrict__ w,
    float* __restrict__ out)
{
    __shared__ float lsXS[K], lsXL[K], lsKM[K], lsILO[K], lsIHI[K];
    __shared__ float lsX[K], lsHI[K], lsGLO[K], lsGHI[K], lsW[K];
    __shared__ float red[2][4][16];
    const int b = blockIdx.x, tid = threadIdx.x;
    const int lane = tid & 63, wv = tid >> 6;
    const float lower = sw[0], upper = sw[1];
    #pragma unroll
    for (int q = 0; q < 4; ++q) {
        int k = tid + q * 256;
        float xk = x[k];
        lsXS[k] = (upper - lower) * xk * (1.0f / SAMPLES);
        lsXL[k] = (1.0f - lower) * xk;
        lsKM[k] = km[k]; lsILO[k] = elo[k]; lsIHI[k] = ehi[k];
        lsX[k] = xk; lsHI[k] = (1.0f + upper) * xk;
        lsGLO[k] = eglo[k]; lsGHI[k] = eghi[k]; lsW[k] = w[k];
    }
    __syncthreads();
    const int sl = tid & 15;          // s-lane within block
    const int kp = tid >> 4;          // 16 k-partials of 64 knots each
    const int s = b * 16 + sl;
    const float xi = (float)s * (1.0f / SAMPLES);
    float rsum = 0.f, esum = 0.f;
    const int k0 = kp * 64;
    #pragma unroll 4
    for (int i = 0; i < 64; ++i) {
        int k = k0 + ((i + kp) & 63);    // stagger: LDS conflict-free across kp
        float g = lsXS[k] * xi + lsXL[k];
        rsum += lsW[k] * gph(g, lsKM[k], lsILO[k], lsIHI[k]);
        float xl = lsXL[k];
        float ge = (lsHI[k] - xl) * xi + xl;
        esum += gph(ge, lsX[k], lsGLO[k], lsGHI[k]);
    }
    // lane = kp_low*16 + sl ; fold kp into lanes 0..15, then across waves
    rsum += __shfl_down(rsum, 32, 64); rsum += __shfl_down(rsum, 16, 64);
    esum += __shfl_down(esum, 32, 64); esum += __shfl_down(esum, 16, 64);
    if (lane < 16) { red[0][wv][lane] = rsum; red[1][wv][lane] = esum; }
    __syncthreads();
    if (tid < 16) {
        float r = red[0][0][tid] + red[0][1][tid] + red[0][2][tid] + red[0][3][tid];
        float e = red[1][0][tid] + red[1][1][tid] + red[1][2][tid] + red[1][3][tid];
        int s2 = b * 16 + tid;
        if (s2 < S) out[s2] = e * r;
    }
}

extern "C" void kernel_launch(void* const* d_in, const int* in_sizes, int n_in,
                              void* d_out, int out_size, void* d_ws, size_t ws_size,
                              hipStream_t stream)
{
    const float* x   = (const float*)d_in[0];
    const float* sw  = (const float*)d_in[1];  // smear_window [lower, upper]
    const float* km  = (const float*)d_in[2];
    const float* kl  = (const float*)d_in[3];
    const float* kh  = (const float*)d_in[4];
    const float* em  = (const float*)d_in[5];
    const float* el  = (const float*)d_in[6];
    const float* eh  = (const float*)d_in[7];
    const float* pol = (const float*)d_in[8];
    float* out = (float*)d_out;

    float* A    = (float*)d_ws;
    float* R    = A + K;
    float* w    = R + K;
    float* elo  = w + K;
    float* ehi  = elo + K;
    float* eel  = ehi + K;
    float* eeh  = eel + K;
    float* eglo = eeh + K;
    float* eghi = eglo + K;

    k_smear<<<K, 256, 0, stream>>>(x, sw, km, kl, kh, el, eh,
                                   A, R, elo, ehi, eel, eeh, eglo, eghi);
    k_entangle<<<K, 256, 0, stream>>>(A, R, em, eel, eeh, pol, w);
    k_accum<<<256, 256, 0, stream>>>(x, sw, km, elo, ehi, eglo, eghi, w, out);
}